// Round 13
// baseline (21.075 us; speedup 1.0000x reference)
//
#include <hip/hip_runtime.h>
#include <stdint.h>

#define B_ 16
#define L_ 256
#define D_ 1024
#define R_ 128
#define M_ (B_*L_)   // 4096 rows of t

typedef short short8 __attribute__((ext_vector_type(8)));
typedef float f32x4 __attribute__((ext_vector_type(4)));

__device__ __forceinline__ unsigned short f2bf(float f) {
  union { float f; unsigned int u; } v; v.f = f;
  unsigned int r = v.u + 0x7FFFu + ((v.u >> 16) & 1u);  // RNE
  return (unsigned short)(r >> 16);
}
__device__ __forceinline__ float bf2f(unsigned short s) {
  union { unsigned int u; float f; } v; v.u = ((unsigned int)s) << 16;
  return v.f;
}
__device__ __forceinline__ void gload_lds16(const void* g, void* l) {
  __builtin_amdgcn_global_load_lds(
      (const __attribute__((address_space(1))) unsigned int*)g,
      (__attribute__((address_space(3))) unsigned int*)l, 16, 0, 0);
}

// ---------------- K0: P [1024][128] f32 -> PbT [128][1024] bf16 ----------------
// 128 blocks: each thread does a k-QUAD (4 strided loads + 8B store).
__global__ __launch_bounds__(256) void k0_transpose_cast(
    const float* __restrict__ P, unsigned short* __restrict__ PbT) {
  int id = blockIdx.x * 256 + threadIdx.x;   // 0..32767
  int n  = id & 127;                         // consecutive across lanes
  int kq = id >> 7;                          // quad of k: 0..255
  union { unsigned short s[4]; uint2 v; } u;
#pragma unroll
  for (int j = 0; j < 4; ++j) u.s[j] = f2bf(P[(kq * 4 + j) * R_ + n]);
  *reinterpret_cast<uint2*>(&PbT[(size_t)n * D_ + kq * 4]) = u.v;
}

// ---------------- K1: t = X @ P  (bf16 MFMA) ----------------
// BM=16, BN=32, BK=128. 128 threads = 2 waves. grid=1024 -> 4 blocks/CU
// (4 independent 2-wave pipelines per CU; LDS 24KB). R7's counted-vmcnt
// schedule, re-derived for 128 threads:
//   per-iter: waitcnt(vmcnt 4, lgkm 0) -> barrier -> compute(buf)
//             -> issueP(buf^1,kt+1) -> loadX(kt+2) -> writeX(buf^1, X(kt+1)).
// All staging into buf^1 happens AFTER barrier@kt (race-free discipline).
__global__ __launch_bounds__(128) void k1_gemm(
    const float* __restrict__ X, const unsigned short* __restrict__ PbT,
    unsigned short* __restrict__ Tb) {
  __shared__ unsigned short sX[2][16 * 128];    // 2 x 4KB, swizzled 256B rows
  __shared__ unsigned short sP[2][32 * 128];    // 2 x 8KB, swizzled 256B rows

  const int tid  = threadIdx.x;
  const int lane = tid & 63;
  const int w    = tid >> 6;          // wave 0..1
  // XCD-bijective swizzle (1024 % 8 == 0): the 4 col-quarter blocks of an
  // m-tile stay on one XCD -> X re-reads are L2-local.
  const int lb   = (blockIdx.x & 7) * 128 + (blockIdx.x >> 3);
  const int m0   = (lb >> 2) * 16;
  const int nb0  = (lb & 3) * 32;

  f32x4 acc;
  acc[0] = 0.f; acc[1] = 0.f; acc[2] = 0.f; acc[3] = 0.f;

  float4 xs[2][4];   // 2 prefetch slots x 4 chunks (statically indexed under unroll)

  auto loadX = [&](float4* slot, int kt) {
#pragma unroll
    for (int i = 0; i < 4; ++i) {
      int c = tid + 128 * i;            // 512 float4 chunks
      int row = c >> 5, kq = (c & 31) * 4;
      slot[i] = *reinterpret_cast<const float4*>(&X[(size_t)(m0 + row) * D_ + kt * 128 + kq]);
    }
  };
  auto writeX = [&](int buf, const float4* slot) {
#pragma unroll
    for (int i = 0; i < 4; ++i) {
      int c = tid + 128 * i;
      int row = c >> 5, kq = (c & 31) * 4;
      uint2 p;
      p.x = (unsigned int)f2bf(slot[i].x) | ((unsigned int)f2bf(slot[i].y) << 16);
      p.y = (unsigned int)f2bf(slot[i].z) | ((unsigned int)f2bf(slot[i].w) << 16);
      int byte_in_row = (kq * 2) ^ ((row & 7) << 4);
      *reinterpret_cast<uint2*>(reinterpret_cast<char*>(&sX[buf][0]) + row * 256 + byte_in_row) = p;
    }
  };
  auto issueP = [&](int buf, int kt) {
    const int k0 = kt * 128;
#pragma unroll
    for (int i = 0; i < 4; ++i) {
      int c = tid + 128 * i;            // 512 chunks of 16B (32 rows x 16)
      int row = c >> 4, ch = c & 15;    // 16 chunks per 256B row
      gload_lds16(&PbT[(size_t)(nb0 + row) * D_ + k0 + ((ch ^ (row & 7)) * 8)],
                  reinterpret_cast<char*>(&sP[buf][0]) + c * 16);
    }
  };
  auto compute = [&](int buf) {
    const char* xb = reinterpret_cast<const char*>(&sX[buf][0]);
    const char* pb = reinterpret_cast<const char*>(&sP[buf][0]);
#pragma unroll
    for (int s = 0; s < 4; ++s) {
      int koffb = s * 64 + ((lane >> 4) << 4);
      int ar = lane & 15;
      short8 a = *reinterpret_cast<const short8*>(xb + ar * 256 + (koffb ^ ((ar & 7) << 4)));
      int br = w * 16 + (lane & 15);
      short8 b = *reinterpret_cast<const short8*>(pb + br * 256 + (koffb ^ ((br & 7) << 4)));
      acc = __builtin_amdgcn_mfma_f32_16x16x32_bf16(a, b, acc, 0, 0, 0);
    }
  };

  // prologue: issue X(0), P(0), X(1); write sX[0] (compiler counted-waits X(0) only)
  loadX(xs[0], 0);
  issueP(0, 0);
  loadX(xs[1], 1);
  writeX(0, xs[0]);
  // outstanding: P(0)x4, X(1)x4

#pragma unroll
  for (int kt = 0; kt < 8; ++kt) {
    const int buf = kt & 1;
    // retire P(kt) (4 oldest); keep X(kt+1) in flight; publish last iter's sX writes
    if (kt == 7) asm volatile("s_waitcnt vmcnt(0) lgkmcnt(0)" ::: "memory");
    else         asm volatile("s_waitcnt vmcnt(4) lgkmcnt(0)" ::: "memory");
    __builtin_amdgcn_sched_barrier(0);
    __builtin_amdgcn_s_barrier();
    compute(buf);
    // staging into buf^1: safe, all waves passed barrier@kt (readers of buf^1 done)
    if (kt < 7) issueP(buf ^ 1, kt + 1);
    if (kt < 6) loadX(xs[kt & 1], kt + 2);
    if (kt < 7) writeX(buf ^ 1, xs[(kt + 1) & 1]);
  }

  // epilogue: write bf16 t
  const int col = lane & 15;
#pragma unroll
  for (int q = 0; q < 4; ++q) {
    int row = ((lane >> 4) << 2) + q;
    Tb[(size_t)(m0 + row) * R_ + nb0 + w * 16 + col] = f2bf(acc[q]);
  }
}

// ---------------- K2: per-batch Gram + distance epilogue ----------------
// block = (b, i-tile it, j-quarter jq). grid=1024 -> 4 blocks/CU. (R7 verbatim.)
__global__ __launch_bounds__(256) void k2_gram(
    const unsigned short* __restrict__ Tb, float* __restrict__ Out) {
  __shared__ unsigned short sI[16 * 128];    // 4KB, swizzled 256B rows
  __shared__ unsigned short sJ[64 * 128];    // 16KB
  __shared__ float nI[16], nJ[64];

  const int tid  = threadIdx.x;
  const int lane = tid & 63;
  const int w    = tid >> 6;        // 0..3
  const int blk  = blockIdx.x;
  const int b    = blk >> 6;
  const int it   = (blk >> 2) & 15;
  const int jq   = blk & 3;

  // stage sI: 256 chunks of 16B (1/thread)
  {
    int row = tid >> 4, ch = tid & 15;
    gload_lds16(&Tb[(size_t)(b * L_ + it * 16 + row) * R_ + ((ch ^ (row & 7)) * 8)],
                reinterpret_cast<char*>(sI) + tid * 16);
  }
  // stage sJ: 1024 chunks (4/thread)
#pragma unroll
  for (int i = 0; i < 4; ++i) {
    int c = tid + 256 * i;
    int row = c >> 4, ch = c & 15;
    gload_lds16(&Tb[(size_t)(b * L_ + jq * 64 + row) * R_ + ((ch ^ (row & 7)) * 8)],
                reinterpret_cast<char*>(sJ) + c * 16);
  }
  __syncthreads();

  // norms: threads 0..159, row = t>>1 (0..15 -> sI, 16..79 -> sJ), half = t&1
  if (tid < 160) {
    int row = tid >> 1, h = tid & 1;
    const char* base = (row < 16) ? reinterpret_cast<const char*>(sI)
                                  : reinterpret_cast<const char*>(sJ);
    int r = (row < 16) ? row : row - 16;
    float s = 0.f;
#pragma unroll
    for (int j = 0; j < 8; ++j) {
      short8 v = *reinterpret_cast<const short8*>(base + r * 256 + ((h * 128 + j * 16) ^ ((r & 7) << 4)));
#pragma unroll
      for (int e = 0; e < 8; ++e) { float f = bf2f((unsigned short)v[e]); s += f * f; }
    }
    s += __shfl_xor(s, 1);
    if (h == 0) { if (row < 16) nI[row] = s; else nJ[row - 16] = s; }
  }

  // Gram via MFMA
  f32x4 acc;
  acc[0] = 0.f; acc[1] = 0.f; acc[2] = 0.f; acc[3] = 0.f;
  const char* ib = reinterpret_cast<const char*>(sI);
  const char* jb = reinterpret_cast<const char*>(sJ);
#pragma unroll
  for (int s = 0; s < 4; ++s) {
    int koffb = s * 64 + ((lane >> 4) << 4);
    int ar = lane & 15;
    short8 a = *reinterpret_cast<const short8*>(ib + ar * 256 + (koffb ^ ((ar & 7) << 4)));
    int br = w * 16 + (lane & 15);
    short8 bv = *reinterpret_cast<const short8*>(jb + br * 256 + (koffb ^ ((br & 7) << 4)));
    acc = __builtin_amdgcn_mfma_f32_16x16x32_bf16(a, bv, acc, 0, 0, 0);
  }
  __syncthreads();   // nI/nJ visible to all

  const int col = lane & 15;
  const int jj = w * 16 + col;
  const float nj = nJ[jj];
#pragma unroll
  for (int q = 0; q < 4; ++q) {
    int ir = ((lane >> 4) << 2) + q;
    float v = nI[ir] + nj - 2.0f * acc[q];
    Out[(size_t)(b * L_ + it * 16 + ir) * L_ + jq * 64 + jj] = fmaxf(v, 0.0f);
  }
}

extern "C" void kernel_launch(void* const* d_in, const int* in_sizes, int n_in,
                              void* d_out, int out_size, void* d_ws, size_t ws_size,
                              hipStream_t stream) {
  const float* X = (const float*)d_in[0];   // [16,256,1024]
  const float* P = (const float*)d_in[1];   // [1024,128]
  float* Out = (float*)d_out;               // [16,256,256]
  char* ws = (char*)d_ws;
  unsigned short* PbT = (unsigned short*)ws;                               // 256 KB
  unsigned short* Tb  = (unsigned short*)(ws + (size_t)R_ * D_ * 2);       // 1 MB

  k0_transpose_cast<<<128, 256, 0, stream>>>(P, PbT);
  k1_gemm<<<1024, 128, 0, stream>>>(X, PbT, Tb);
  k2_gram<<<B_ * 16 * 4, 256, 0, stream>>>(Tb, Out);
}